// Round 5
// baseline (187.368 us; speedup 1.0000x reference)
//
#include <hip/hip_runtime.h>
#include <hip/hip_bf16.h>

// SimpleTransformer fused implementation for MI355X (gfx950).
// B=8, L=1024, E=16, DK=64, set_dim=32, vdim=8, head=256.
//
// Stage map:
//  prep_kernel : q/k projections (->bf16), V-MLP, SetPhi-MLP (->bf16 transposed), zero summar
//  attn_kernel : per (b, 16-row i-tile): bf16 MFMA QK^T -> sigmoid(+offset, diag=0)
//                -> LDS atomic scatter into A2[i,d] += attn[i,j], d=|i-j|
//                -> sv = A2 @ SetPhi via MFMA (K=1024)
//                -> summar[b,sd,k] += sum_i sv[i,sd]*v[i,k] (global atomic)
//  head_kernel : 256->256->256->4 MLP + softmax

#define LSEQ 1024
#define DK   64
#define EMB  16
#define VDIM 8

typedef __attribute__((ext_vector_type(8))) short bf16x8;
typedef __attribute__((ext_vector_type(4))) float f32x4;

__device__ __forceinline__ unsigned short f2bf(float f) {
  union { float f; unsigned u; } v; v.f = f;
  unsigned r = v.u + 0x7fffu + ((v.u >> 16) & 1u);  // round-to-nearest-even
  return (unsigned short)(r >> 16);
}

__device__ __forceinline__ f32x4 mfma16(bf16x8 a, bf16x8 b, f32x4 c) {
  return __builtin_amdgcn_mfma_f32_16x16x32_bf16(a, b, c, 0, 0, 0);
}

// ---------------------------------------------------------------------------
// prep: block ranges  [0,4096) q/k proj | [4096,4608) V-MLP | [4608,4864) SetPhi | [4864,4872) zero
// ---------------------------------------------------------------------------
__global__ __launch_bounds__(256) void prep_kernel(
    const float* __restrict__ x,  const float* __restrict__ WQ,  const float* __restrict__ WK,
    const float* __restrict__ VW1, const float* __restrict__ Vb1,
    const float* __restrict__ VW2, const float* __restrict__ Vb2,
    const float* __restrict__ VW3, const float* __restrict__ Vb3,
    const float* __restrict__ PW1, const float* __restrict__ Pb1,
    const float* __restrict__ PW2, const float* __restrict__ Pb2,
    const float* __restrict__ PW3, const float* __restrict__ Pb3,
    const float* __restrict__ PW4, const float* __restrict__ Pb4,
    unsigned short* __restrict__ qb, unsigned short* __restrict__ kb,
    unsigned short* __restrict__ phiT, float* __restrict__ vws,
    float* __restrict__ summar)
{
  __shared__ float s1[272];
  __shared__ float s2[272];
  int bid = blockIdx.x, tid = threadIdx.x;

  if (bid < 4096) {
    // q/k projection: one output element per thread. 128 threads span q[0..63],k[0..63] of one row.
    int g = bid * 256 + tid;
    int row = g >> 7, c = g & 127;
    const float* xr = x + row * EMB;
    const float* wr = ((c < 64) ? WQ : WK) + (c & 63) * EMB;
    float acc = 0.f;
    #pragma unroll
    for (int e = 0; e < 4; ++e) {
      f32x4 xv = *(const f32x4*)(xr + e * 4);
      f32x4 wv = *(const f32x4*)(wr + e * 4);
      acc += xv[0]*wv[0] + xv[1]*wv[1] + xv[2]*wv[2] + xv[3]*wv[3];
    }
    unsigned short* dst = (c < 64) ? qb : kb;
    dst[row * DK + (c & 63)] = f2bf(acc);

  } else if (bid < 4608) {
    // V MLP: 16 rows/block, 16 threads/row
    int lb = bid - 4096;
    int r = tid >> 4, cc = tid & 15;
    int row = lb * 16 + r;
    const float* xr = x + row * EMB;
    float acc = Vb1[cc];
    #pragma unroll
    for (int e4 = 0; e4 < 4; ++e4) {
      f32x4 wv = *(const f32x4*)(VW1 + cc * 16 + e4 * 4);
      acc += xr[e4*4+0]*wv[0] + xr[e4*4+1]*wv[1] + xr[e4*4+2]*wv[2] + xr[e4*4+3]*wv[3];
    }
    s1[r * 17 + cc] = fmaxf(acc, 0.f);
    __syncthreads();
    acc = Vb2[cc];
    #pragma unroll
    for (int e4 = 0; e4 < 4; ++e4) {
      f32x4 wv = *(const f32x4*)(VW2 + cc * 16 + e4 * 4);
      acc += s1[r*17+e4*4+0]*wv[0] + s1[r*17+e4*4+1]*wv[1] + s1[r*17+e4*4+2]*wv[2] + s1[r*17+e4*4+3]*wv[3];
    }
    s2[r * 17 + cc] = fmaxf(acc, 0.f);
    __syncthreads();
    if (cc < 8) {
      acc = Vb3[cc];
      #pragma unroll
      for (int e4 = 0; e4 < 4; ++e4) {
        f32x4 wv = *(const f32x4*)(VW3 + cc * 16 + e4 * 4);
        acc += s2[r*17+e4*4+0]*wv[0] + s2[r*17+e4*4+1]*wv[1] + s2[r*17+e4*4+2]*wv[2] + s2[r*17+e4*4+3]*wv[3];
      }
      vws[row * VDIM + cc] = 1.f / (1.f + __expf(-acc));
    }

  } else if (bid < 4864) {
    // SetPhi MLP over t=row/1023: 4 rows/block, 64 threads/row. Output transposed bf16 [32][1024].
    int lb = bid - 4608;
    int r = tid >> 6, cc = tid & 63;
    int row = lb * 4 + r;
    float t = (float)row * (1.0f / 1023.0f);
    s1[r * 65 + cc] = fmaxf(PW1[cc] * t + Pb1[cc], 0.f);
    __syncthreads();
    float acc = Pb2[cc];
    #pragma unroll
    for (int e4 = 0; e4 < 16; ++e4) {
      f32x4 wv = *(const f32x4*)(PW2 + cc * 64 + e4 * 4);
      acc += s1[r*65+e4*4+0]*wv[0] + s1[r*65+e4*4+1]*wv[1] + s1[r*65+e4*4+2]*wv[2] + s1[r*65+e4*4+3]*wv[3];
    }
    s2[r * 65 + cc] = fmaxf(acc, 0.f);
    __syncthreads();
    acc = Pb3[cc];
    #pragma unroll
    for (int e4 = 0; e4 < 16; ++e4) {
      f32x4 wv = *(const f32x4*)(PW3 + cc * 64 + e4 * 4);
      acc += s2[r*65+e4*4+0]*wv[0] + s2[r*65+e4*4+1]*wv[1] + s2[r*65+e4*4+2]*wv[2] + s2[r*65+e4*4+3]*wv[3];
    }
    s1[r * 65 + cc] = fmaxf(acc, 0.f);   // safe: all reads of old s1 completed before prior barrier
    __syncthreads();
    if (cc < 32) {
      acc = Pb4[cc];
      #pragma unroll
      for (int e4 = 0; e4 < 16; ++e4) {
        f32x4 wv = *(const f32x4*)(PW4 + cc * 64 + e4 * 4);
        acc += s1[r*65+e4*4+0]*wv[0] + s1[r*65+e4*4+1]*wv[1] + s1[r*65+e4*4+2]*wv[2] + s1[r*65+e4*4+3]*wv[3];
      }
      phiT[cc * LSEQ + row] = f2bf(acc);  // phiT[c][d] = SetPhi[d][c]
    }

  } else {
    // zero summarized accumulator (ws is poisoned before every call)
    int idx = (bid - 4864) * 256 + tid;
    summar[idx] = 0.f;
  }
}

// ---------------------------------------------------------------------------
// attn: grid = 8 b * 64 i-tiles = 512 blocks, 256 threads (4 waves).
// Barrier-free t-loop: sigmoid values scatter directly into A2 via LDS atomics.
// ---------------------------------------------------------------------------
__global__ __launch_bounds__(256) void attn_kernel(
    const unsigned short* __restrict__ qb, const unsigned short* __restrict__ kb,
    const unsigned short* __restrict__ phiT, const float* __restrict__ vws,
    const float* __restrict__ offs, float* __restrict__ summar)
{
  __shared__ float A2_s[16 * 1026];     // fp32 folded-diagonal accumulator, stride 1026
  __shared__ float sv_w[4][16][17];     // per-wave sv GEMM partials
  __shared__ float v_s[16][8];

  int bid = blockIdx.x;
  int b  = bid >> 6;
  int i0 = (bid & 63) << 4;
  int tid = threadIdx.x;
  int lane = tid & 63, w = tid >> 6;
  int lr = lane & 15, lg = lane >> 4;

  for (int idx = tid; idx < 16 * 1026; idx += 256) A2_s[idx] = 0.f;
  if (tid < 128) v_s[tid >> 3][tid & 7] = vws[(b * LSEQ + i0 + (tid >> 3)) * VDIM + (tid & 7)];

  float off = offs[0];

  // A fragments (q rows i0..i0+15), reused for all j: lane holds q[i0+lr][k-window]
  const unsigned short* qrow = qb + (size_t)(b * LSEQ + i0 + lr) * DK + lg * 8;
  bf16x8 afr0 = *(const bf16x8*)qrow;         // k = 0..31 window
  bf16x8 afr1 = *(const bf16x8*)(qrow + 32);  // k = 32..63 window

  const unsigned short* kbase = kb + (size_t)b * LSEQ * DK;
  int jbl = (w * 2) * 16;  // this wave's first local j-subtile column

  // prefetch tile 0 B-fragments
  const unsigned short* kr = kbase + (jbl + lr) * DK + lg * 8;
  bf16x8 b00 = *(const bf16x8*)kr;
  bf16x8 b01 = *(const bf16x8*)(kr + 32);
  bf16x8 b10 = *(const bf16x8*)(kr + 16 * DK);
  bf16x8 b11 = *(const bf16x8*)(kr + 16 * DK + 32);

  __syncthreads();  // A2_s zero + v_s visible

  for (int t = 0; t < 8; ++t) {
    int j0 = t * 128;
    // ---- scores: 16x16x32 bf16 MFMA, K=64 chained ----
    f32x4 acc0 = {0.f, 0.f, 0.f, 0.f}, acc1 = {0.f, 0.f, 0.f, 0.f};
    acc0 = mfma16(afr0, b00, acc0);
    acc0 = mfma16(afr1, b01, acc0);
    acc1 = mfma16(afr0, b10, acc1);
    acc1 = mfma16(afr1, b11, acc1);
    // prefetch next tile's B-fragments (hidden under sigmoid+scatter)
    if (t < 7) {
      const unsigned short* kr2 = kbase + ((t + 1) * 128 + jbl + lr) * DK + lg * 8;
      b00 = *(const bf16x8*)kr2;
      b01 = *(const bf16x8*)(kr2 + 32);
      b10 = *(const bf16x8*)(kr2 + 16 * DK);
      b11 = *(const bf16x8*)(kr2 + 16 * DK + 32);
    }
    // ---- sigmoid + diag mask + scatter. D layout: row=(lane>>4)*4+r, col=lane&15 ----
    #pragma unroll
    for (int r2 = 0; r2 < 4; ++r2) {
      int row = 4 * lg + r2;
      int gi = i0 + row;
      int gj0 = j0 + jbl + lr;
      int gj1 = gj0 + 16;
      float s0 = (gi == gj0) ? 0.f : 1.f / (1.f + __expf(-(acc0[r2] * 0.125f + off)));
      float s1v = (gi == gj1) ? 0.f : 1.f / (1.f + __expf(-(acc1[r2] * 0.125f + off)));
      int d0 = gi - gj0; d0 = (d0 < 0) ? -d0 : d0;
      int d1 = gi - gj1; d1 = (d1 < 0) ? -d1 : d1;
      atomicAdd(&A2_s[row * 1026 + d0], s0);   // ds_add_f32
      atomicAdd(&A2_s[row * 1026 + d1], s1v);
    }
  }
  __syncthreads();  // all scatters done before sv GEMM reads A2_s

  // ---- sv = A2 (16x1024) @ SetPhi (1024x32) via MFMA; wave: ct=c-tile, kh=K-half ----
  {
    int ct = w & 1, kh = w >> 1;
    f32x4 acc = {0.f, 0.f, 0.f, 0.f};
    const unsigned short* ph = phiT + (ct * 16 + lr) * LSEQ + kh * 512 + lg * 8;
    const float* arow = A2_s + lr * 1026 + kh * 512 + lg * 8;
    for (int s = 0; s < 16; ++s) {
      bf16x8 af;
      const float* ap = arow + s * 32;
      #pragma unroll
      for (int e = 0; e < 8; ++e) af[e] = (short)f2bf(ap[e]);
      bf16x8 bfv = *(const bf16x8*)(ph + s * 32);
      acc = mfma16(af, bfv, acc);
    }
    #pragma unroll
    for (int r2 = 0; r2 < 4; ++r2)
      sv_w[w][4 * lg + r2][lr] = acc[r2];
  }
  __syncthreads();

  // ---- summarized partial: summar[b][sd][k] += sum_i sv[i][sd] * v[i][k] ----
  {
    int sd = tid >> 3, kk = tid & 7;   // sd in [0,32), kk in [0,8)
    int ct = sd >> 4, cl = sd & 15;
    float a = 0.f;
    #pragma unroll
    for (int il = 0; il < 16; ++il)
      a += (sv_w[ct][il][cl] + sv_w[ct + 2][il][cl]) * v_s[il][kk];
    unsafeAtomicAdd(&summar[b * 256 + sd * 8 + kk], a);
  }
}

// ---------------------------------------------------------------------------
// head: 8 blocks (one per batch), 1024 threads
// ---------------------------------------------------------------------------
__global__ __launch_bounds__(1024) void head_kernel(
    const float* __restrict__ summar,
    const float* __restrict__ HW1, const float* __restrict__ Hb1,
    const float* __restrict__ HW2, const float* __restrict__ Hb2,
    const float* __restrict__ HW3, const float* __restrict__ Hb3,
    float* __restrict__ out)
{
  __shared__ float fb[256];
  __shared__ float part[4][260];
  __shared__ float lgt[4];
  int b = blockIdx.x, tid = threadIdx.x;
  int c = tid & 255, qt = tid >> 8;

  if (qt == 0) fb[c] = summar[b * 256 + c];
  __syncthreads();
  // layer 1
  {
    const float* wr = HW1 + c * 256 + qt * 64;
    const float* xr = fb + qt * 64;
    float a = 0.f;
    #pragma unroll
    for (int e = 0; e < 16; ++e) {
      f32x4 wv = *(const f32x4*)(wr + e * 4);
      f32x4 xv = *(const f32x4*)(xr + e * 4);
      a += wv[0]*xv[0] + wv[1]*xv[1] + wv[2]*xv[2] + wv[3]*xv[3];
    }
    part[qt][c] = a;
  }
  __syncthreads();
  if (qt == 0)
    fb[c] = fmaxf(part[0][c] + part[1][c] + part[2][c] + part[3][c] + Hb1[c], 0.f);
  __syncthreads();
  // layer 2
  {
    const float* wr = HW2 + c * 256 + qt * 64;
    const float* xr = fb + qt * 64;
    float a = 0.f;
    #pragma unroll
    for (int e = 0; e < 16; ++e) {
      f32x4 wv = *(const f32x4*)(wr + e * 4);
      f32x4 xv = *(const f32x4*)(xr + e * 4);
      a += wv[0]*xv[0] + wv[1]*xv[1] + wv[2]*xv[2] + wv[3]*xv[3];
    }
    part[qt][c] = a;
  }
  __syncthreads();
  if (qt == 0)
    fb[c] = fmaxf(part[0][c] + part[1][c] + part[2][c] + part[3][c] + Hb2[c], 0.f);
  __syncthreads();
  // layer 3 + softmax
  if (tid < 4) {
    float a = Hb3[tid];
    for (int e = 0; e < 256; ++e) a += fb[e] * HW3[tid * 256 + e];
    lgt[tid] = a;
  }
  __syncthreads();
  if (tid == 0) {
    float m = fmaxf(fmaxf(lgt[0], lgt[1]), fmaxf(lgt[2], lgt[3]));
    float e0 = __expf(lgt[0] - m), e1 = __expf(lgt[1] - m);
    float e2 = __expf(lgt[2] - m), e3 = __expf(lgt[3] - m);
    float s = e0 + e1 + e2 + e3;
    out[b * 4 + 0] = e0 / s;
    out[b * 4 + 1] = e1 / s;
    out[b * 4 + 2] = e2 / s;
    out[b * 4 + 3] = e3 / s;
  }
}

// ---------------------------------------------------------------------------
extern "C" void kernel_launch(void* const* d_in, const int* in_sizes, int n_in,
                              void* d_out, int out_size, void* d_ws, size_t ws_size,
                              hipStream_t stream)
{
  const float* x   = (const float*)d_in[0];
  const float* WQ  = (const float*)d_in[1];
  const float* WK  = (const float*)d_in[2];
  const float* VW1 = (const float*)d_in[3];
  const float* Vb1 = (const float*)d_in[4];
  const float* VW2 = (const float*)d_in[5];
  const float* Vb2 = (const float*)d_in[6];
  const float* VW3 = (const float*)d_in[7];
  const float* Vb3 = (const float*)d_in[8];
  const float* PW1 = (const float*)d_in[9];
  const float* Pb1 = (const float*)d_in[10];
  const float* PW2 = (const float*)d_in[11];
  const float* Pb2 = (const float*)d_in[12];
  const float* PW3 = (const float*)d_in[13];
  const float* Pb3 = (const float*)d_in[14];
  const float* PW4 = (const float*)d_in[15];
  const float* Pb4 = (const float*)d_in[16];
  const float* offs= (const float*)d_in[17];
  const float* HW1 = (const float*)d_in[18];
  const float* Hb1 = (const float*)d_in[19];
  const float* HW2 = (const float*)d_in[20];
  const float* Hb2 = (const float*)d_in[21];
  const float* HW3 = (const float*)d_in[22];
  const float* Hb3 = (const float*)d_in[23];

  // workspace carve (bytes): qb 1MB | kb 1MB | phiT 64KB | v 256KB | summar 8KB
  char* ws = (char*)d_ws;
  unsigned short* qb   = (unsigned short*)(ws);
  unsigned short* kb   = (unsigned short*)(ws + (1u << 20));
  unsigned short* phiT = (unsigned short*)(ws + (2u << 20));
  float* vws    = (float*)(ws + (2u << 20) + (1u << 16));
  float* summar = (float*)(ws + (2u << 20) + (1u << 16) + (1u << 18));

  prep_kernel<<<dim3(4872), dim3(256), 0, stream>>>(
      x, WQ, WK, VW1, Vb1, VW2, Vb2, VW3, Vb3,
      PW1, Pb1, PW2, Pb2, PW3, Pb3, PW4, Pb4,
      qb, kb, phiT, vws, summar);

  attn_kernel<<<dim3(512), dim3(256), 0, stream>>>(
      qb, kb, phiT, vws, offs, summar);

  head_kernel<<<dim3(8), dim3(1024), 0, stream>>>(
      summar, HW1, Hb1, HW2, Hb2, HW3, Hb3, (float*)d_out);
}